// Round 8
// baseline (64.642 us; speedup 1.0000x reference)
//
#include <hip/hip_runtime.h>

constexpr int D = 64;  // D_FEAT == UNITS == 64

typedef float nfloat4 __attribute__((ext_vector_type(4)));  // builtin-compatible

// ---------------------------------------------------------------------------
// Kernel A (edge-centric, x4 vectorized): offs[n] = lower_bound(ids, n).
// ---------------------------------------------------------------------------
__global__ void seg_bounds(const int* __restrict__ ids, int* __restrict__ offs,
                           int n_nodes, int n_edges) {
    const int t  = blockIdx.x * blockDim.x + threadIdx.x;
    const int e0 = t * 4;
    if (e0 >= n_edges) return;
    const int4 c4   = *(const int4*)(ids + e0);
    const int  prev = (e0 == 0) ? -1 : ids[e0 - 1];
    const int  cur[4] = {c4.x, c4.y, c4.z, c4.w};
    int p = prev;
#pragma unroll
    for (int u = 0; u < 4; ++u) {
        const int e = e0 + u;
        for (int n = p + 1; n <= cur[u]; ++n) offs[n] = e;
        p = cur[u];
    }
    if (e0 + 4 >= n_edges) {
        for (int n = p + 1; n <= n_nodes; ++n) offs[n] = n_edges;
    }
}

// ---------------------------------------------------------------------------
// Kernel B: TWO nodes per wave; PER-SEGMENT quad-aligned streaming.
// Each segment: full 16-row quads of pure v_add (NT loads, no predication),
// then ONE tail quad with single-weight fmaf + in-segment clamp. This removes
// the s1-crossing boundary quad of the union-stream version (R7) and halves
// tail VALU (1 weight instead of 2). HBM bytes identical.
// ---------------------------------------------------------------------------
template <bool USE_OFFS>
__global__ __launch_bounds__(256, 8) void gcn_fused(
    const float* __restrict__ src,   // [N, 64]
    const float* __restrict__ dst,   // [E, 64]
    const int*   __restrict__ ids,   // [E] sorted (fallback path only)
    const int*   __restrict__ offs,  // [N+1] segment offsets
    const float* __restrict__ Wm,    // [64, 64]
    const float* __restrict__ bv,    // [64]
    float*       __restrict__ out,   // [N, 64]
    int n_nodes, int n_edges)
{
    __shared__ float sW[D][D];   // 16 KB (DS port, not vmem — R4 lesson)
    __shared__ float sx[8][D];   // 2 KB

    const int tid = threadIdx.x;
    {
        const float4* W4  = (const float4*)Wm;
        float4*       sW4 = (float4*)&sW[0][0];
#pragma unroll
        for (int i = 0; i < 4; ++i) sW4[tid + 256 * i] = W4[tid + 256 * i];
    }
    __syncthreads();  // only barrier; before any divergent exit

    const int wave = tid >> 6;
    const int lane = tid & 63;
    const int n0   = (blockIdx.x * 4 + wave) * 2;  // even node
    if (n0 >= n_nodes) return;  // never taken (50000 % 8 == 0)

    int s0, s1, s2;
    if (USE_OFFS) {
        const int2 o01 = *(const int2*)(offs + n0);  // n0 even -> 8B aligned
        s0 = o01.x; s1 = o01.y;
        s2 = offs[n0 + 2];
    } else {
        int key = n0 + (lane >> 5);
        int lo = 0, hi = n_edges;
        while (lo < hi) { const int mid = (lo + hi) >> 1; if (ids[mid] < key) lo = mid + 1; else hi = mid; }
        s0 = __shfl(lo, 0); s1 = __shfl(lo, 32);
        int lo2 = 0, hi2 = n_edges; const int key2 = n0 + 2;
        while (lo2 < hi2) { const int mid = (lo2 + hi2) >> 1; if (ids[mid] < key2) lo2 = mid + 1; else hi2 = mid; }
        s2 = lo2;
    }

    const int g = lane >> 4;   // group g reads row q + 4u + g
    const int f = lane & 15;   // float4 chunk within a 256B row
    const int h = g & 1;

    // Prefetch BOTH src rows early (contiguous 512B, lanes 0..31).
    float4 s4 = make_float4(0.f, 0.f, 0.f, 0.f);
    if (lane < 32) s4 = *((const float4*)src + (size_t)n0 * (D / 4) + lane);

    const nfloat4* dst4 = (const nfloat4*)dst;

    // Per-segment sum over [s, e): full quads (pure adds) + one tail quad
    // (single weight + clamp; clamped rows stay inside [s, e) -> L1-hot).
    auto seg_sum = [&](int s, int e) -> float4 {
        float4 a = make_float4(0.f, 0.f, 0.f, 0.f);
        int q = s;
#pragma unroll 1
        for (; q + 16 <= e; q += 16) {   // wave-uniform condition: s_cbranch
#pragma unroll
            for (int u = 0; u < 4; ++u) {
                const int r = q + 4 * u + g;
                const nfloat4 v = __builtin_nontemporal_load(&dst4[r * (D / 4) + f]);
                a.x += v.x; a.y += v.y; a.z += v.z; a.w += v.w;
            }
        }
        if (q < e) {                     // tail quad (uniform branch)
            const int last = e - 1;
#pragma unroll
            for (int u = 0; u < 4; ++u) {
                const int r  = q + 4 * u + g;
                const int rc = min(r, last);
                const nfloat4 v = __builtin_nontemporal_load(&dst4[rc * (D / 4) + f]);
                const float w = (r < e) ? 1.0f : 0.0f;
                a.x = fmaf(w, v.x, a.x);
                a.y = fmaf(w, v.y, a.y);
                a.z = fmaf(w, v.z, a.z);
                a.w = fmaf(w, v.w, a.w);
            }
        }
        return a;
    };

    float4 a0 = seg_sum(s0, s1);
    float4 a1 = seg_sum(s1, s2);

    // Reduce 4 groups for both accumulators.
    a0.x += __shfl_xor(a0.x, 16); a0.y += __shfl_xor(a0.y, 16);
    a0.z += __shfl_xor(a0.z, 16); a0.w += __shfl_xor(a0.w, 16);
    a1.x += __shfl_xor(a1.x, 16); a1.y += __shfl_xor(a1.y, 16);
    a1.z += __shfl_xor(a1.z, 16); a1.w += __shfl_xor(a1.w, 16);
    a0.x += __shfl_xor(a0.x, 32); a0.y += __shfl_xor(a0.y, 32);
    a0.z += __shfl_xor(a0.z, 32); a0.w += __shfl_xor(a0.w, 32);
    a1.x += __shfl_xor(a1.x, 32); a1.y += __shfl_xor(a1.y, 32);
    a1.z += __shfl_xor(a1.z, 32); a1.w += __shfl_xor(a1.w, 32);

    // x = mean + src: lanes 0..15 -> node0, 16..31 -> node1 (512B LDS write).
    if (lane < 32) {
        const int   cnt = h ? (s2 - s1) : (s1 - s0);
        const float inv = 1.0f / fmaxf((float)cnt, 1.0f);
        const float4 av = h ? a1 : a0;
        float4 xv;
        xv.x = fmaf(av.x, inv, s4.x);
        xv.y = fmaf(av.y, inv, s4.y);
        xv.z = fmaf(av.z, inv, s4.z);
        xv.w = fmaf(av.w, inv, s4.w);
        *((float4*)&sx[wave * 2][0] + lane) = xv;
    }
    // same-wave LDS RAW: compiler inserts lgkmcnt wait; no barrier needed.

    // out[n][lane] = b[lane] + sum_k x[k]*W[k][lane]; W read feeds both nodes.
    const float bvl = bv[lane];
    float acc_a = bvl, acc_b = bvl;
#pragma unroll
    for (int k = 0; k < D; k += 4) {
        const float4 x0 = *(const float4*)&sx[wave * 2][k];      // broadcast
        const float4 x1 = *(const float4*)&sx[wave * 2 + 1][k];  // broadcast
#pragma unroll
        for (int j = 0; j < 4; ++j) {
            const float w = sW[k + j][lane];                     // stride-1
            acc_a = fmaf((&x0.x)[j], w, acc_a);
            acc_b = fmaf((&x1.x)[j], w, acc_b);
        }
    }
    __builtin_nontemporal_store(acc_a, &out[(size_t)n0 * D + lane]);
    __builtin_nontemporal_store(acc_b, &out[(size_t)(n0 + 1) * D + lane]);
}

extern "C" void kernel_launch(void* const* d_in, const int* in_sizes, int n_in,
                              void* d_out, int out_size, void* d_ws, size_t ws_size,
                              hipStream_t stream) {
    const float* src = (const float*)d_in[0];
    // d_in[1] = edge (unused by reference)
    const float* dst = (const float*)d_in[2];
    const int*   ids = (const int*)d_in[3];
    const float* Wm  = (const float*)d_in[4];
    const float* bv  = (const float*)d_in[5];
    float* out = (float*)d_out;

    const int n_nodes = in_sizes[0] / D;   // 50000
    const int n_edges = in_sizes[3];       // 1250000

    const int nblocks = (n_nodes + 7) / 8; // 6250 (8 nodes per block)

    if (ws_size >= (size_t)(n_nodes + 1) * sizeof(int)) {
        int* offs = (int*)d_ws;
        const int t4 = (n_edges + 3) / 4;
        seg_bounds<<<(t4 + 255) / 256, 256, 0, stream>>>(ids, offs, n_nodes, n_edges);
        gcn_fused<true><<<nblocks, 256, 0, stream>>>(src, dst, ids, offs, Wm, bv, out,
                                                     n_nodes, n_edges);
    } else {
        gcn_fused<false><<<nblocks, 256, 0, stream>>>(src, dst, ids, nullptr, Wm, bv, out,
                                                      n_nodes, n_edges);
    }
}

// Round 9
// 59.927 us; speedup vs baseline: 1.0787x; 1.0787x over previous
//
#include <hip/hip_runtime.h>

constexpr int D = 64;  // D_FEAT == UNITS == 64

typedef float nfloat4 __attribute__((ext_vector_type(4)));  // builtin-compatible

// ---------------------------------------------------------------------------
// Kernel A (edge-centric, x4 vectorized): offs[n] = lower_bound(ids, n).
// ---------------------------------------------------------------------------
__global__ void seg_bounds(const int* __restrict__ ids, int* __restrict__ offs,
                           int n_nodes, int n_edges) {
    const int t  = blockIdx.x * blockDim.x + threadIdx.x;
    const int e0 = t * 4;
    if (e0 >= n_edges) return;
    const int4 c4   = *(const int4*)(ids + e0);
    const int  prev = (e0 == 0) ? -1 : ids[e0 - 1];
    const int  cur[4] = {c4.x, c4.y, c4.z, c4.w};
    int p = prev;
#pragma unroll
    for (int u = 0; u < 4; ++u) {
        const int e = e0 + u;
        for (int n = p + 1; n <= cur[u]; ++n) offs[n] = e;
        p = cur[u];
    }
    if (e0 + 4 >= n_edges) {
        for (int n = p + 1; n <= n_nodes; ++n) offs[n] = n_edges;
    }
}

// ---------------------------------------------------------------------------
// Kernel B (R7 structure — best measured: 59.4 us): TWO nodes per wave,
// UNION-stream quad-uniform branch streaming. Per 16-row quad the membership
// condition is wave-uniform (s_cbranch):
//   interior quads: unpredicated v_add, no clamp, nontemporal load
//   boundary quads: fmaf-by-{0,1} weights
// R8 lesson: per-segment split streaming regressed (64.6) — keep ONE loop.
// ---------------------------------------------------------------------------
template <bool USE_OFFS>
__global__ __launch_bounds__(256, 8) void gcn_fused(
    const float* __restrict__ src,   // [N, 64]
    const float* __restrict__ dst,   // [E, 64]
    const int*   __restrict__ ids,   // [E] sorted (fallback path only)
    const int*   __restrict__ offs,  // [N+1] segment offsets
    const float* __restrict__ Wm,    // [64, 64]
    const float* __restrict__ bv,    // [64]
    float*       __restrict__ out,   // [N, 64]
    int n_nodes, int n_edges)
{
    __shared__ float sW[D][D];   // 16 KB (DS port, not vmem — R4 lesson)
    __shared__ float sx[8][D];   // 2 KB

    const int tid = threadIdx.x;
    {
        const float4* W4  = (const float4*)Wm;
        float4*       sW4 = (float4*)&sW[0][0];
#pragma unroll
        for (int i = 0; i < 4; ++i) sW4[tid + 256 * i] = W4[tid + 256 * i];
    }
    __syncthreads();  // only barrier; before any divergent exit

    const int wave = tid >> 6;
    const int lane = tid & 63;
    const int n0   = (blockIdx.x * 4 + wave) * 2;  // even node
    if (n0 >= n_nodes) return;  // never taken (50000 % 8 == 0)

    int s0, s1, s2;
    if (USE_OFFS) {
        const int2 o01 = *(const int2*)(offs + n0);  // n0 even -> 8B aligned
        s0 = o01.x; s1 = o01.y;
        s2 = offs[n0 + 2];
    } else {
        int key = n0 + (lane >> 5);
        int lo = 0, hi = n_edges;
        while (lo < hi) { const int mid = (lo + hi) >> 1; if (ids[mid] < key) lo = mid + 1; else hi = mid; }
        s0 = __shfl(lo, 0); s1 = __shfl(lo, 32);
        int lo2 = 0, hi2 = n_edges; const int key2 = n0 + 2;
        while (lo2 < hi2) { const int mid = (lo2 + hi2) >> 1; if (ids[mid] < key2) lo2 = mid + 1; else hi2 = mid; }
        s2 = lo2;
    }

    const int g = lane >> 4;   // group g reads row q0 + 4u + g
    const int f = lane & 15;   // float4 chunk within a 256B row
    const int h = g & 1;

    // Prefetch BOTH src rows early (contiguous 512B, lanes 0..31).
    float4 s4 = make_float4(0.f, 0.f, 0.f, 0.f);
    if (lane < 32) s4 = *((const float4*)src + (size_t)n0 * (D / 4) + lane);

    const nfloat4* dst4 = (const nfloat4*)dst;
    float4 a0 = make_float4(0.f, 0.f, 0.f, 0.f);
    float4 a1 = make_float4(0.f, 0.f, 0.f, 0.f);

    const int total = s2 - s0;
    const int nb    = (total + 3) >> 2;   // 4-row batches
    const int nb4   = (nb + 3) & ~3;      // round to quad of batches
    const int last  = s2 - 1;             // clamp (valid iff total>0)

#pragma unroll 1
    for (int b = 0; b < nb4; b += 4) {
        const int q0   = s0 + 4 * b;      // first row of this 16-row quad
        const int qend = q0 + 16;         // one past last row
        if (qend <= s1) {
            // ---- interior node0: all rows valid & belong to a0 ----
#pragma unroll
            for (int u = 0; u < 4; ++u) {
                const int r = q0 + 4 * u + g;
                const nfloat4 v = __builtin_nontemporal_load(&dst4[r * (D / 4) + f]);
                a0.x += v.x; a0.y += v.y; a0.z += v.z; a0.w += v.w;
            }
        } else if (q0 >= s1 && qend <= s2) {
            // ---- interior node1 ----
#pragma unroll
            for (int u = 0; u < 4; ++u) {
                const int r = q0 + 4 * u + g;
                const nfloat4 v = __builtin_nontemporal_load(&dst4[r * (D / 4) + f]);
                a1.x += v.x; a1.y += v.y; a1.z += v.z; a1.w += v.w;
            }
        } else {
            // ---- boundary / tail quad: weight-by-{0,1} fmaf ----
#pragma unroll
            for (int u = 0; u < 4; ++u) {
                const int r  = q0 + 4 * u + g;
                const int rc = min(r, last);             // clamp: L1-hot real row
                const nfloat4 v = dst4[rc * (D / 4) + f];
                const float w0 = (r < s1) ? 1.0f : 0.0f;
                const float w1 = ((r >= s1) & (r < s2)) ? 1.0f : 0.0f;
                a0.x = fmaf(w0, v.x, a0.x);  a1.x = fmaf(w1, v.x, a1.x);
                a0.y = fmaf(w0, v.y, a0.y);  a1.y = fmaf(w1, v.y, a1.y);
                a0.z = fmaf(w0, v.z, a0.z);  a1.z = fmaf(w1, v.z, a1.z);
                a0.w = fmaf(w0, v.w, a0.w);  a1.w = fmaf(w1, v.w, a1.w);
            }
        }
    }

    // Reduce 4 groups for both accumulators.
    a0.x += __shfl_xor(a0.x, 16); a0.y += __shfl_xor(a0.y, 16);
    a0.z += __shfl_xor(a0.z, 16); a0.w += __shfl_xor(a0.w, 16);
    a1.x += __shfl_xor(a1.x, 16); a1.y += __shfl_xor(a1.y, 16);
    a1.z += __shfl_xor(a1.z, 16); a1.w += __shfl_xor(a1.w, 16);
    a0.x += __shfl_xor(a0.x, 32); a0.y += __shfl_xor(a0.y, 32);
    a0.z += __shfl_xor(a0.z, 32); a0.w += __shfl_xor(a0.w, 32);
    a1.x += __shfl_xor(a1.x, 32); a1.y += __shfl_xor(a1.y, 32);
    a1.w += __shfl_xor(a1.w, 32); a1.z += __shfl_xor(a1.z, 32);

    // x = mean + src: lanes 0..15 -> node0, 16..31 -> node1 (512B LDS write).
    if (lane < 32) {
        const int   cnt = h ? (s2 - s1) : (s1 - s0);
        const float inv = 1.0f / fmaxf((float)cnt, 1.0f);
        const float4 av = h ? a1 : a0;
        float4 xv;
        xv.x = fmaf(av.x, inv, s4.x);
        xv.y = fmaf(av.y, inv, s4.y);
        xv.z = fmaf(av.z, inv, s4.z);
        xv.w = fmaf(av.w, inv, s4.w);
        *((float4*)&sx[wave * 2][0] + lane) = xv;
    }
    // same-wave LDS RAW: compiler inserts lgkmcnt wait; no barrier needed.

    // out[n][lane] = b[lane] + sum_k x[k]*W[k][lane]; W read feeds both nodes.
    const float bvl = bv[lane];
    float acc_a = bvl, acc_b = bvl;
#pragma unroll
    for (int k = 0; k < D; k += 4) {
        const float4 x0 = *(const float4*)&sx[wave * 2][k];      // broadcast
        const float4 x1 = *(const float4*)&sx[wave * 2 + 1][k];  // broadcast
#pragma unroll
        for (int j = 0; j < 4; ++j) {
            const float w = sW[k + j][lane];                     // stride-1
            acc_a = fmaf((&x0.x)[j], w, acc_a);
            acc_b = fmaf((&x1.x)[j], w, acc_b);
        }
    }
    __builtin_nontemporal_store(acc_a, &out[(size_t)n0 * D + lane]);
    __builtin_nontemporal_store(acc_b, &out[(size_t)(n0 + 1) * D + lane]);
}

extern "C" void kernel_launch(void* const* d_in, const int* in_sizes, int n_in,
                              void* d_out, int out_size, void* d_ws, size_t ws_size,
                              hipStream_t stream) {
    const float* src = (const float*)d_in[0];
    // d_in[1] = edge (unused by reference)
    const float* dst = (const float*)d_in[2];
    const int*   ids = (const int*)d_in[3];
    const float* Wm  = (const float*)d_in[4];
    const float* bv  = (const float*)d_in[5];
    float* out = (float*)d_out;

    const int n_nodes = in_sizes[0] / D;   // 50000
    const int n_edges = in_sizes[3];       // 1250000

    const int nblocks = (n_nodes + 7) / 8; // 6250 (8 nodes per block)

    if (ws_size >= (size_t)(n_nodes + 1) * sizeof(int)) {
        int* offs = (int*)d_ws;
        const int t4 = (n_edges + 3) / 4;
        seg_bounds<<<(t4 + 255) / 256, 256, 0, stream>>>(ids, offs, n_nodes, n_edges);
        gcn_fused<true><<<nblocks, 256, 0, stream>>>(src, dst, ids, offs, Wm, bv, out,
                                                     n_nodes, n_edges);
    } else {
        gcn_fused<false><<<nblocks, 256, 0, stream>>>(src, dst, ids, nullptr, Wm, bv, out,
                                                      n_nodes, n_edges);
    }
}